// Round 11
// baseline (74.085 us; speedup 1.0000x reference)
//
#include <hip/hip_runtime.h>
#include <cstddef>

#define B_ 2
#define C_ 32
#define CP 33
#define W_ 256
#define H_ 256
#define X_ 512
#define Y_ 512

typedef __bf16 bf16x8 __attribute__((ext_vector_type(8)));
typedef __bf16 bf16x4 __attribute__((ext_vector_type(4)));
typedef float  f32x4  __attribute__((ext_vector_type(4)));

#define AS1 __attribute__((address_space(1)))
#define AS3 __attribute__((address_space(3)))

__device__ __forceinline__ void gload16_lds(const void* g, void* l) {
    // async global->LDS, 16B/lane, LDS dest = wave-uniform base + lane*16
    __builtin_amdgcn_global_load_lds((const AS1 void*)g, (AS3 void*)l, 16, 0, 0);
}

// ws layout (bf16):
//   wlonT [B][X][W], wlatT [B][Y][H], wt33 [B][CP][W][H], U_T [B][CP][Y][W]

// ---------------- prep: bf16 tables ----------------
__global__ __launch_bounds__(256) void prep_kernel(
    const float* __restrict__ xin_lon, const float* __restrict__ xin_lat,
    const float* __restrict__ xout_lon, const float* __restrict__ xout_lat,
    const float* __restrict__ init_ls, const float* __restrict__ wt,
    __bf16* __restrict__ wlonT, __bf16* __restrict__ wlatT,
    __bf16* __restrict__ wt33)
{
    const int NLON = B_ * X_ * W_;
    const int NLAT = B_ * Y_ * H_;
    int t = blockIdx.x * 256 + threadIdx.x;
    float ls = init_ls[0];
    float cc = -0.5f / (ls * ls);
    if (t < NLON) {
        int b = t / (X_ * W_);
        int r = t - b * (X_ * W_);
        int x = r >> 8;
        int w = r & (W_ - 1);
        float d = xin_lon[b * W_ + w] - xout_lon[b * X_ + x];
        wlonT[t] = (__bf16)__expf(cc * d * d);
    } else if (t < NLON + NLAT) {
        int j = t - NLON;
        int b = j / (Y_ * H_);
        int r = j - b * (Y_ * H_);
        int y = r >> 8;
        int h = r & (H_ - 1);
        float d = xin_lat[b * H_ + h] - xout_lat[b * Y_ + y];
        wlatT[j] = (__bf16)__expf(cc * d * d);
    } else {
        int j = t - (NLON + NLAT);
        int o = j * 4;
        int b = o / (CP * W_ * H_);
        int r = o - b * (CP * W_ * H_);
        int co = r / (W_ * H_);
        int p = r & (W_ * H_ - 1);
        float4 v;
        bf16x4 ov;
        if (co == 0) {
            v = *(const float4*)&wt[((size_t)b * C_) * (W_ * H_) + p];
            ov[0] = (__bf16)((v.x != v.x) ? 0.f : 1.f);
            ov[1] = (__bf16)((v.y != v.y) ? 0.f : 1.f);
            ov[2] = (__bf16)((v.z != v.z) ? 0.f : 1.f);
            ov[3] = (__bf16)((v.w != v.w) ? 0.f : 1.f);
        } else {
            v = *(const float4*)&wt[((size_t)b * C_ + (co - 1)) * (W_ * H_) + p];
            ov[0] = (__bf16)((v.x != v.x) ? 0.f : v.x);
            ov[1] = (__bf16)((v.y != v.y) ? 0.f : v.y);
            ov[2] = (__bf16)((v.z != v.z) ? 0.f : v.z);
            ov[3] = (__bf16)((v.w != v.w) ? 0.f : v.w);
        }
        *(bf16x4*)&wt33[o] = ov;
    }
}

// ---------------- stage 1: U_T = (wt33 x wlatT^T)^T ----------------
// 128(w) x 64(y) x K256 tiles, 1056 blocks. Round-10 lesson: 1-deep
// prefetch left every phase stalled ~300-600cyc on vmcnt (load latency
// 500-900 > phase ~350), and lockstep blocks make stalls correlated.
// Now: 4-slot ring, prefetch 3 ahead, steady vmcnt(9) (3 loads/stage).
__global__ __launch_bounds__(256, 4) void gemm_u(
    const __bf16* __restrict__ wt33, const __bf16* __restrict__ wlatT,
    __bf16* __restrict__ U_T)
{
    __shared__ union SM {
        struct { __bf16 A[4][4096]; __bf16 Bt[4][2048]; } t;  // 48 KB
        __bf16 th[8704];     // 64 x 136 (bf16 transpose, padded)
    } sm;

    const int t    = threadIdx.x;
    const int lane = t & 63;
    const int wave = t >> 6;
    const int wm   = wave >> 1, wn = wave & 1;
    const int lrow = lane & 15, lkg = lane >> 4;

    // bijective chunked XCD swizzle (1056 % 8 == 0): panel p's 16 tiles
    // land on one XCD -> wt33/wlatT panels L2-resident.
    const int xcd = blockIdx.x & 7, k = blockIdx.x >> 3;  // k: 0..131
    const int m   = xcd * 132 + k;
    const int p   = m >> 4, tile = m & 15;
    const int mtile = tile >> 3, ntile = tile & 7;        // 2(w) x 8(y)
    const int bb = (p >= CP) ? 1 : 0, chh = p - bb * CP;
    const __bf16* Abase = wt33 + (size_t)p * (W_ * H_) + (size_t)mtile * 128 * H_;
    const __bf16* Bbase = wlatT + (size_t)bb * (Y_ * H_) + (size_t)ntile * 64 * H_;

    auto stage = [&](int buf, int kt) {
#pragma unroll
        for (int j = 0; j < 2; ++j) {
            int f = j * 4 + wave;                          // A frags 0..7
            gload16_lds((const void*)(Abase + (f * 16 + lrow) * H_ + kt * 32 + lkg * 8),
                        (void*)&sm.t.A[buf][f * 512]);
        }
        gload16_lds((const void*)(Bbase + (wave * 16 + lrow) * H_ + kt * 32 + lkg * 8),
                    (void*)&sm.t.Bt[buf][wave * 512]);     // B frags 0..3
    };

    f32x4 acc[4][2] = {};
    stage(0, 0);
    stage(1, 1);
    stage(2, 2);
#pragma unroll
    for (int kt = 0; kt < 8; ++kt) {
        const int buf = kt & 3;
        if (kt <= 4) {
            stage((kt + 3) & 3, kt + 3);
            asm volatile("s_waitcnt vmcnt(9)" ::: "memory");   // stage kt landed
        } else if (kt == 5) {
            asm volatile("s_waitcnt vmcnt(6)" ::: "memory");
        } else if (kt == 6) {
            asm volatile("s_waitcnt vmcnt(3)" ::: "memory");
        } else {
            asm volatile("s_waitcnt vmcnt(0)" ::: "memory");
        }
        __builtin_amdgcn_s_barrier();
        bf16x8 af[4], bf[2];
#pragma unroll
        for (int mt = 0; mt < 4; ++mt)
            af[mt] = *(const bf16x8*)&sm.t.A[buf][((wm * 4 + mt) * 64 + lane) * 8];
#pragma unroll
        for (int nt = 0; nt < 2; ++nt)
            bf[nt] = *(const bf16x8*)&sm.t.Bt[buf][((wn * 2 + nt) * 64 + lane) * 8];
#pragma unroll
        for (int mt = 0; mt < 4; ++mt)
#pragma unroll
            for (int nt = 0; nt < 2; ++nt)
                acc[mt][nt] = __builtin_amdgcn_mfma_f32_16x16x32_bf16(
                    af[mt], bf[nt], acc[mt][nt], 0, 0, 0);
        __builtin_amdgcn_sched_barrier(0);
        __builtin_amdgcn_s_barrier();
    }

    // block-cooperative bf16 transpose -> U_T rows [y][w], 256B spans
#pragma unroll
    for (int mt = 0; mt < 4; ++mt)
#pragma unroll
        for (int nt = 0; nt < 2; ++nt) {
            int yloc = wn * 32 + nt * 16 + lrow;
            int wloc = wm * 64 + mt * 16 + lkg * 4;
            f32x4 c = acc[mt][nt];
            bf16x4 v4;
            v4[0] = (__bf16)c[0]; v4[1] = (__bf16)c[1];
            v4[2] = (__bf16)c[2]; v4[3] = (__bf16)c[3];
            *(bf16x4*)&sm.th[yloc * 136 + wloc] = v4;
        }
    __syncthreads();
    __bf16* up = U_T + (size_t)(bb * CP + chh) * (Y_ * W_);
#pragma unroll
    for (int it = 0; it < 4; ++it) {
        int c2 = it * 256 + t;
        int y = c2 >> 4, w8 = c2 & 15;
        bf16x8 v = *(const bf16x8*)&sm.th[y * 136 + w8 * 8];
        *(bf16x8*)&up[(size_t)(ntile * 64 + y) * W_ + mtile * 128 + w8 * 8] = v;
    }
}

// ---------------- stage 2 fused: all 33 channels + divide ----------------
// Per block: (b, x-tile 64, y-tile 64, channel group of 4) -> 1024 blocks.
//   B = wlonT x-panel, LDS-RESIDENT 32 KB, staged once.
//   A = U_T y-panel, streamed per BK=32 through a 4-SLOT ring, prefetch 3
//       ahead, steady vmcnt(3) (1 load/thread/stage), flat 40-phase loop.
// Operand-role swap: C row = y -> direct coalesced f32x4 stores.
__global__ __launch_bounds__(256, 4) void stage2_fused(
    const __bf16* __restrict__ wlonT, const __bf16* __restrict__ U_T,
    float* __restrict__ out)
{
    __shared__ __bf16 Blon[16384];      // 32 KB resident x-panel, frag-linear
    __shared__ __bf16 Ast[4][2048];     // 16 KB: 4-slot ring, 4 KB per kt

    const int t = threadIdx.x, lane = t & 63, wave = t >> 6;
    const int lrow = lane & 15, lkg = lane >> 4;
    const int wm = wave >> 1, wn = wave & 1;

    const int bid  = blockIdx.x;
    const int xcd  = bid & 7, r = bid >> 3;        // r: 0..127
    const int pair = r >> 6, rem = r & 63;
    const int yt   = rem >> 3, g = rem & 7;
    const int bxt  = xcd * 2 + pair;               // same (b,xt) per XCD
    const int b    = bxt >> 3, xt = bxt & 7;
    const int x0   = xt * 64, y0 = yt * 64;

    const __bf16* lonp = wlonT + ((size_t)b * X_ + x0) * W_;
    const __bf16* Apan[5];
#pragma unroll
    for (int j = 0; j < 5; ++j) {
        int ch = (j == 0) ? 0 : (g * 4 + j);
        Apan[j] = U_T + (size_t)(b * CP + ch) * (Y_ * W_) + (size_t)y0 * W_;
    }

    // resident B: frag f = kt*4 + nf; wave stages f = i*4+wave, i=kt
    {
        const int srcoff = (wave * 16 + lrow) * W_ + lkg * 8;
#pragma unroll
        for (int i = 0; i < 8; ++i)
            gload16_lds((const void*)(lonp + srcoff + i * 32),
                        (void*)&Blon[(i * 4 + wave) * 512]);
    }
    // A stream: per tile 4 frags (one per wave); tile j: pass j>>3, kt j&7
    auto stageA = [&](int slot, int j) {
        const __bf16* src = Apan[j >> 3] + (size_t)(wave * 16 + lrow) * W_
                            + (j & 7) * 32 + lkg * 8;
        gload16_lds((const void*)src, (void*)&Ast[slot][wave * 512]);
    };

    stageA(0, 0);
    stageA(1, 1);
    stageA(2, 2);

    f32x4 rec[2][2];
#pragma unroll
    for (int p = 0; p < 5; ++p) {
        f32x4 acc[2][2] = {};
#pragma unroll
        for (int kt = 0; kt < 8; ++kt) {
            const int s = p * 8 + kt;
            const int slot = s & 3;
            if (s <= 36) {
                stageA((s + 3) & 3, s + 3);
                asm volatile("s_waitcnt vmcnt(3)" ::: "memory");  // tile s landed
            } else if (s == 37) {
                asm volatile("s_waitcnt vmcnt(2)" ::: "memory");
            } else if (s == 38) {
                asm volatile("s_waitcnt vmcnt(1)" ::: "memory");
            } else {
                asm volatile("s_waitcnt vmcnt(0)" ::: "memory");
            }
            __builtin_amdgcn_s_barrier();
            bf16x8 af[2], bfv[2];
#pragma unroll
            for (int mt = 0; mt < 2; ++mt)
                af[mt] = *(const bf16x8*)&Ast[slot][((wm * 2 + mt) * 64 + lane) * 8];
#pragma unroll
            for (int nt = 0; nt < 2; ++nt)
                bfv[nt] = *(const bf16x8*)&Blon[((kt * 4 + wn * 2 + nt) * 64 + lane) * 8];
#pragma unroll
            for (int mt = 0; mt < 2; ++mt)
#pragma unroll
                for (int nt = 0; nt < 2; ++nt)
                    acc[mt][nt] = __builtin_amdgcn_mfma_f32_16x16x32_bf16(
                        af[mt], bfv[nt], acc[mt][nt], 0, 0, 0);
            __builtin_amdgcn_sched_barrier(0);
            __builtin_amdgcn_s_barrier();
        }

        if (p == 0) {
#pragma unroll
            for (int mt = 0; mt < 2; ++mt)
#pragma unroll
                for (int nt = 0; nt < 2; ++nt) {
                    f32x4 c = acc[mt][nt], q;
#pragma unroll
                    for (int rr = 0; rr < 4; ++rr)
                        q[rr] = 1.0f / fminf(fmaxf(c[rr], 1e-6f), 1e5f);
                    rec[mt][nt] = q;
                }
            if (g == 0) {
                float* outc = out + (size_t)(b * CP) * (X_ * Y_);
#pragma unroll
                for (int mt = 0; mt < 2; ++mt)
#pragma unroll
                    for (int nt = 0; nt < 2; ++nt) {
                        int xg = x0 + (wn * 2 + nt) * 16 + lrow;
                        int yg = y0 + (wm * 2 + mt) * 16 + lkg * 4;
                        *(f32x4*)&outc[(size_t)xg * Y_ + yg] = acc[mt][nt];
                    }
            }
        } else {
            float* outc = out + (size_t)(b * CP + g * 4 + p) * (size_t)(X_ * Y_);
#pragma unroll
            for (int mt = 0; mt < 2; ++mt)
#pragma unroll
                for (int nt = 0; nt < 2; ++nt) {
                    int xg = x0 + (wn * 2 + nt) * 16 + lrow;
                    int yg = y0 + (wm * 2 + mt) * 16 + lkg * 4;
                    f32x4 v = acc[mt][nt] * rec[mt][nt];
                    *(f32x4*)&outc[(size_t)xg * Y_ + yg] = v;
                }
        }
    }
}

extern "C" void kernel_launch(void* const* d_in, const int* in_sizes, int n_in,
                              void* d_out, int out_size, void* d_ws, size_t ws_size,
                              hipStream_t stream)
{
    const float* xin_lon  = (const float*)d_in[0];
    const float* xin_lat  = (const float*)d_in[1];
    const float* wt       = (const float*)d_in[2];
    const float* xout_lon = (const float*)d_in[3];
    const float* xout_lat = (const float*)d_in[4];
    const float* init_ls  = (const float*)d_in[5];
    float* out = (float*)d_out;

    __bf16* wlonT = (__bf16*)d_ws;
    __bf16* wlatT = wlonT + (size_t)B_ * X_ * W_;
    __bf16* wt33  = wlatT + (size_t)B_ * Y_ * H_;
    __bf16* U_T   = wt33 + (size_t)B_ * CP * W_ * H_;

    prep_kernel<<<6272, 256, 0, stream>>>(xin_lon, xin_lat, xout_lon, xout_lat,
                                          init_ls, wt, wlonT, wlatT, wt33);
    gemm_u<<<1056, 256, 0, stream>>>(wt33, wlatT, U_T);
    stage2_fused<<<1024, 256, 0, stream>>>(wlonT, U_T, out);
}

// Round 12
// 70.554 us; speedup vs baseline: 1.0500x; 1.0500x over previous
//
#include <hip/hip_runtime.h>
#include <cstddef>

#define B_ 2
#define C_ 32
#define CP 33
#define W_ 256
#define H_ 256
#define X_ 512
#define Y_ 512

typedef __bf16 bf16x8 __attribute__((ext_vector_type(8)));
typedef __bf16 bf16x4 __attribute__((ext_vector_type(4)));
typedef float  f32x4  __attribute__((ext_vector_type(4)));

#define AS1 __attribute__((address_space(1)))
#define AS3 __attribute__((address_space(3)))

__device__ __forceinline__ void gload16_lds(const void* g, void* l) {
    // async global->LDS, 16B/lane, LDS dest = wave-uniform base + lane*16
    __builtin_amdgcn_global_load_lds((const AS1 void*)g, (AS3 void*)l, 16, 0, 0);
}

// ws layout (bf16):
//   wlonT [B][X][W], wlatT [B][Y][H], wt33 [B][CP][W][H], U_T [B][CP][Y][W]

// ---------------- prep: bf16 tables ----------------
__global__ __launch_bounds__(256) void prep_kernel(
    const float* __restrict__ xin_lon, const float* __restrict__ xin_lat,
    const float* __restrict__ xout_lon, const float* __restrict__ xout_lat,
    const float* __restrict__ init_ls, const float* __restrict__ wt,
    __bf16* __restrict__ wlonT, __bf16* __restrict__ wlatT,
    __bf16* __restrict__ wt33)
{
    const int NLON = B_ * X_ * W_;
    const int NLAT = B_ * Y_ * H_;
    int t = blockIdx.x * 256 + threadIdx.x;
    float ls = init_ls[0];
    float cc = -0.5f / (ls * ls);
    if (t < NLON) {
        int b = t / (X_ * W_);
        int r = t - b * (X_ * W_);
        int x = r >> 8;
        int w = r & (W_ - 1);
        float d = xin_lon[b * W_ + w] - xout_lon[b * X_ + x];
        wlonT[t] = (__bf16)__expf(cc * d * d);
    } else if (t < NLON + NLAT) {
        int j = t - NLON;
        int b = j / (Y_ * H_);
        int r = j - b * (Y_ * H_);
        int y = r >> 8;
        int h = r & (H_ - 1);
        float d = xin_lat[b * H_ + h] - xout_lat[b * Y_ + y];
        wlatT[j] = (__bf16)__expf(cc * d * d);
    } else {
        int j = t - (NLON + NLAT);
        int o = j * 4;
        int b = o / (CP * W_ * H_);
        int r = o - b * (CP * W_ * H_);
        int co = r / (W_ * H_);
        int p = r & (W_ * H_ - 1);
        float4 v;
        bf16x4 ov;
        if (co == 0) {
            v = *(const float4*)&wt[((size_t)b * C_) * (W_ * H_) + p];
            ov[0] = (__bf16)((v.x != v.x) ? 0.f : 1.f);
            ov[1] = (__bf16)((v.y != v.y) ? 0.f : 1.f);
            ov[2] = (__bf16)((v.z != v.z) ? 0.f : 1.f);
            ov[3] = (__bf16)((v.w != v.w) ? 0.f : 1.f);
        } else {
            v = *(const float4*)&wt[((size_t)b * C_ + (co - 1)) * (W_ * H_) + p];
            ov[0] = (__bf16)((v.x != v.x) ? 0.f : v.x);
            ov[1] = (__bf16)((v.y != v.y) ? 0.f : v.y);
            ov[2] = (__bf16)((v.z != v.z) ? 0.f : v.z);
            ov[3] = (__bf16)((v.w != v.w) ? 0.f : v.w);
        }
        *(bf16x4*)&wt33[o] = ov;
    }
}

// ---------------- stage 1: U_T = (wt33 x wlatT^T)^T ----------------
// Round-10 config (best so far): 128(w) x 64(y) x K256, 1056 blocks =
// 4/CU, 2-slot ring, counted vmcnt(3). Epilogue: LDS transpose ->
// 256B-span writes of U_T[b][ch][y][w].
__global__ __launch_bounds__(256, 4) void gemm_u(
    const __bf16* __restrict__ wt33, const __bf16* __restrict__ wlatT,
    __bf16* __restrict__ U_T)
{
    __shared__ union SM {
        struct { __bf16 A[2][4096]; __bf16 Bt[2][2048]; } t;  // 24 KB
        __bf16 th[8704];     // 64 x 136 (bf16 transpose, padded)
    } sm;

    const int t    = threadIdx.x;
    const int lane = t & 63;
    const int wave = t >> 6;
    const int wm   = wave >> 1, wn = wave & 1;
    const int lrow = lane & 15, lkg = lane >> 4;

    // bijective chunked XCD swizzle (1056 % 8 == 0): panel p's 16 tiles
    // land on one XCD -> wt33/wlatT panels L2-resident.
    const int xcd = blockIdx.x & 7, k = blockIdx.x >> 3;  // k: 0..131
    const int m   = xcd * 132 + k;
    const int p   = m >> 4, tile = m & 15;
    const int mtile = tile >> 3, ntile = tile & 7;        // 2(w) x 8(y)
    const int bb = (p >= CP) ? 1 : 0, chh = p - bb * CP;
    const __bf16* Abase = wt33 + (size_t)p * (W_ * H_) + (size_t)mtile * 128 * H_;
    const __bf16* Bbase = wlatT + (size_t)bb * (Y_ * H_) + (size_t)ntile * 64 * H_;

    auto stage = [&](int buf, int kt) {
#pragma unroll
        for (int j = 0; j < 2; ++j) {
            int f = j * 4 + wave;                          // A frags 0..7
            gload16_lds((const void*)(Abase + (f * 16 + lrow) * H_ + kt * 32 + lkg * 8),
                        (void*)&sm.t.A[buf][f * 512]);
        }
        gload16_lds((const void*)(Bbase + (wave * 16 + lrow) * H_ + kt * 32 + lkg * 8),
                    (void*)&sm.t.Bt[buf][wave * 512]);     // B frags 0..3
    };

    f32x4 acc[4][2] = {};
    stage(0, 0);
#pragma unroll
    for (int kt = 0; kt < 8; ++kt) {
        const int buf = kt & 1;
        if (kt < 7) {
            stage(buf ^ 1, kt + 1);
            asm volatile("s_waitcnt vmcnt(3)" ::: "memory");  // cur tile landed
        } else {
            asm volatile("s_waitcnt vmcnt(0)" ::: "memory");
        }
        __builtin_amdgcn_s_barrier();
        bf16x8 af[4], bf[2];
#pragma unroll
        for (int mt = 0; mt < 4; ++mt)
            af[mt] = *(const bf16x8*)&sm.t.A[buf][((wm * 4 + mt) * 64 + lane) * 8];
#pragma unroll
        for (int nt = 0; nt < 2; ++nt)
            bf[nt] = *(const bf16x8*)&sm.t.Bt[buf][((wn * 2 + nt) * 64 + lane) * 8];
#pragma unroll
        for (int mt = 0; mt < 4; ++mt)
#pragma unroll
            for (int nt = 0; nt < 2; ++nt)
                acc[mt][nt] = __builtin_amdgcn_mfma_f32_16x16x32_bf16(
                    af[mt], bf[nt], acc[mt][nt], 0, 0, 0);
        __builtin_amdgcn_sched_barrier(0);
        __builtin_amdgcn_s_barrier();
    }

    // block-cooperative bf16 transpose -> U_T rows [y][w], 256B spans
#pragma unroll
    for (int mt = 0; mt < 4; ++mt)
#pragma unroll
        for (int nt = 0; nt < 2; ++nt) {
            int yloc = wn * 32 + nt * 16 + lrow;
            int wloc = wm * 64 + mt * 16 + lkg * 4;
            f32x4 c = acc[mt][nt];
            bf16x4 v4;
            v4[0] = (__bf16)c[0]; v4[1] = (__bf16)c[1];
            v4[2] = (__bf16)c[2]; v4[3] = (__bf16)c[3];
            *(bf16x4*)&sm.th[yloc * 136 + wloc] = v4;
        }
    __syncthreads();
    __bf16* up = U_T + (size_t)(bb * CP + chh) * (Y_ * W_);
#pragma unroll
    for (int it = 0; it < 4; ++it) {
        int c2 = it * 256 + t;
        int y = c2 >> 4, w8 = c2 & 15;
        bf16x8 v = *(const bf16x8*)&sm.th[y * 136 + w8 * 8];
        *(bf16x8*)&up[(size_t)(ntile * 64 + y) * W_ + mtile * 128 + w8 * 8] = v;
    }
}

// ---------------- stage 2 fused: channel-merged mega-phases ----------------
// Per block: (b, x-tile 64, y-tile 64, channel group of 4) -> 1024 blocks.
// Round-11 lesson: 4 MFMA per barrier-phase x 40 phases = fixed phase cost
// dominates (MfmaUtil pinned at 8%). Now all 5 channels (ch0 + group) are
// computed INSIDE each k-phase: per phase stage 24KB (5 A-tiles + B k-slice,
// 3-slot ring, prefetch 2, steady vmcnt(12)), 12 ds_read, 20 MFMA -> only
// 8 phases per block. rec from acc[0] at the end; C-quad = 4 consecutive y
// at fixed x -> direct coalesced f32x4 stores.
__global__ __launch_bounds__(256, 2) void stage2_fused(
    const __bf16* __restrict__ wlonT, const __bf16* __restrict__ U_T,
    float* __restrict__ out)
{
    __shared__ __bf16 Ast[3][12288];    // 72 KB: 3 slots x (20 A + 4 B frags)

    const int t = threadIdx.x, lane = t & 63, wave = t >> 6;
    const int lrow = lane & 15, lkg = lane >> 4;
    const int wm = wave >> 1, wn = wave & 1;

    const int bid  = blockIdx.x;
    const int xcd  = bid & 7, r = bid >> 3;        // r: 0..127
    const int pair = r >> 6, rem = r & 63;
    const int yt   = rem >> 3, g = rem & 7;
    const int bxt  = xcd * 2 + pair;               // same (b,xt) per XCD
    const int b    = bxt >> 3, xt = bxt & 7;
    const int x0   = xt * 64, y0 = yt * 64;

    const __bf16* lonp  = wlonT + ((size_t)b * X_ + x0) * W_;
    const __bf16* Ubase = U_T + ((size_t)b * CP) * (Y_ * W_) + (size_t)y0 * W_;

    // staging: 24 frags/phase (frag jf: jf<20 -> A ch=jf>>2, row-quad jf&3;
    // jf>=20 -> B frag jf-20). Each wave stages frags wave*6..wave*6+5.
    // Pointers computed arithmetically (rule #20: no runtime-indexed array).
    auto stage = [&](int slot, int kt) {
#pragma unroll
        for (int i = 0; i < 6; ++i) {
            const int jf = wave * 6 + i;
            const __bf16* src;
            if (jf < 20) {
                const int jj = jf >> 2;
                const int ch = (jj == 0) ? 0 : (g * 4 + jj);
                src = Ubase + (size_t)ch * (Y_ * W_)
                      + ((jf & 3) * 16 + lrow) * W_ + kt * 32 + lkg * 8;
            } else {
                src = lonp + ((jf - 20) * 16 + lrow) * W_ + kt * 32 + lkg * 8;
            }
            gload16_lds((const void*)src, (void*)&Ast[slot][jf * 512]);
        }
    };

    stage(0, 0);
    stage(1, 1);

    f32x4 acc[5][2][2] = {};
#pragma unroll
    for (int kt = 0; kt < 8; ++kt) {
        const int slot = kt % 3;
        if (kt <= 5) {
            stage((kt + 2) % 3, kt + 2);
            asm volatile("s_waitcnt vmcnt(12)" ::: "memory");  // phase kt landed
        } else if (kt == 6) {
            asm volatile("s_waitcnt vmcnt(6)" ::: "memory");
        } else {
            asm volatile("s_waitcnt vmcnt(0)" ::: "memory");
        }
        __builtin_amdgcn_s_barrier();
        bf16x8 af[5][2], bfv[2];
#pragma unroll
        for (int j = 0; j < 5; ++j)
#pragma unroll
            for (int mt = 0; mt < 2; ++mt)
                af[j][mt] = *(const bf16x8*)
                    &Ast[slot][((j * 4 + wm * 2 + mt) * 64 + lane) * 8];
#pragma unroll
        for (int nt = 0; nt < 2; ++nt)
            bfv[nt] = *(const bf16x8*)
                &Ast[slot][((20 + wn * 2 + nt) * 64 + lane) * 8];
        asm volatile("s_waitcnt lgkmcnt(0)" ::: "memory");
        __builtin_amdgcn_sched_barrier(0);
#pragma unroll
        for (int j = 0; j < 5; ++j)
#pragma unroll
            for (int mt = 0; mt < 2; ++mt)
#pragma unroll
                for (int nt = 0; nt < 2; ++nt)
                    acc[j][mt][nt] = __builtin_amdgcn_mfma_f32_16x16x32_bf16(
                        af[j][mt], bfv[nt], acc[j][mt][nt], 0, 0, 0);
        __builtin_amdgcn_sched_barrier(0);
        __builtin_amdgcn_s_barrier();   // slot safe to overwrite next phase
    }

    // ---- epilogue: rec from density acc, divide, store ----
    f32x4 rec[2][2];
#pragma unroll
    for (int mt = 0; mt < 2; ++mt)
#pragma unroll
        for (int nt = 0; nt < 2; ++nt) {
            f32x4 c = acc[0][mt][nt], q;
#pragma unroll
            for (int rr = 0; rr < 4; ++rr)
                q[rr] = 1.0f / fminf(fmaxf(c[rr], 1e-6f), 1e5f);
            rec[mt][nt] = q;
        }
    if (g == 0) {
        float* outc = out + (size_t)(b * CP) * (X_ * Y_);
#pragma unroll
        for (int mt = 0; mt < 2; ++mt)
#pragma unroll
            for (int nt = 0; nt < 2; ++nt) {
                int xg = x0 + (wn * 2 + nt) * 16 + lrow;
                int yg = y0 + (wm * 2 + mt) * 16 + lkg * 4;
                *(f32x4*)&outc[(size_t)xg * Y_ + yg] = acc[0][mt][nt];
            }
    }
#pragma unroll
    for (int j = 1; j < 5; ++j) {
        float* outc = out + (size_t)(b * CP + g * 4 + j) * (size_t)(X_ * Y_);
#pragma unroll
        for (int mt = 0; mt < 2; ++mt)
#pragma unroll
            for (int nt = 0; nt < 2; ++nt) {
                int xg = x0 + (wn * 2 + nt) * 16 + lrow;
                int yg = y0 + (wm * 2 + mt) * 16 + lkg * 4;
                f32x4 v = acc[j][mt][nt] * rec[mt][nt];
                *(f32x4*)&outc[(size_t)xg * Y_ + yg] = v;
            }
    }
}

extern "C" void kernel_launch(void* const* d_in, const int* in_sizes, int n_in,
                              void* d_out, int out_size, void* d_ws, size_t ws_size,
                              hipStream_t stream)
{
    const float* xin_lon  = (const float*)d_in[0];
    const float* xin_lat  = (const float*)d_in[1];
    const float* wt       = (const float*)d_in[2];
    const float* xout_lon = (const float*)d_in[3];
    const float* xout_lat = (const float*)d_in[4];
    const float* init_ls  = (const float*)d_in[5];
    float* out = (float*)d_out;

    __bf16* wlonT = (__bf16*)d_ws;
    __bf16* wlatT = wlonT + (size_t)B_ * X_ * W_;
    __bf16* wt33  = wlatT + (size_t)B_ * Y_ * H_;
    __bf16* U_T   = wt33 + (size_t)B_ * CP * W_ * H_;

    prep_kernel<<<6272, 256, 0, stream>>>(xin_lon, xin_lat, xout_lon, xout_lat,
                                          init_ls, wt, wlonT, wlatT, wt33);
    gemm_u<<<1056, 256, 0, stream>>>(wt33, wlatT, U_T);
    stage2_fused<<<1024, 256, 0, stream>>>(wlonT, U_T, out);
}

// Round 13
// 61.783 us; speedup vs baseline: 1.1991x; 1.1420x over previous
//
#include <hip/hip_runtime.h>
#include <cstddef>

#define B_ 2
#define C_ 32
#define CP 33
#define W_ 256
#define H_ 256
#define X_ 512
#define Y_ 512

typedef __bf16 bf16x8 __attribute__((ext_vector_type(8)));
typedef __bf16 bf16x4 __attribute__((ext_vector_type(4)));
typedef float  f32x4  __attribute__((ext_vector_type(4)));

#define AS1 __attribute__((address_space(1)))
#define AS3 __attribute__((address_space(3)))

__device__ __forceinline__ void gload16_lds(const void* g, void* l) {
    // async global->LDS, 16B/lane, LDS dest = wave-uniform base + lane*16
    __builtin_amdgcn_global_load_lds((const AS1 void*)g, (AS3 void*)l, 16, 0, 0);
}

// ws layout (bf16):
//   wlonT [B][X][W], wlatT [B][Y][H], wt33 [B][CP][W][H], U_T [B][CP][Y][W]

// ---------------- prep: bf16 tables ----------------
__global__ __launch_bounds__(256) void prep_kernel(
    const float* __restrict__ xin_lon, const float* __restrict__ xin_lat,
    const float* __restrict__ xout_lon, const float* __restrict__ xout_lat,
    const float* __restrict__ init_ls, const float* __restrict__ wt,
    __bf16* __restrict__ wlonT, __bf16* __restrict__ wlatT,
    __bf16* __restrict__ wt33)
{
    const int NLON = B_ * X_ * W_;
    const int NLAT = B_ * Y_ * H_;
    int t = blockIdx.x * 256 + threadIdx.x;
    float ls = init_ls[0];
    float cc = -0.5f / (ls * ls);
    if (t < NLON) {
        int b = t / (X_ * W_);
        int r = t - b * (X_ * W_);
        int x = r >> 8;
        int w = r & (W_ - 1);
        float d = xin_lon[b * W_ + w] - xout_lon[b * X_ + x];
        wlonT[t] = (__bf16)__expf(cc * d * d);
    } else if (t < NLON + NLAT) {
        int j = t - NLON;
        int b = j / (Y_ * H_);
        int r = j - b * (Y_ * H_);
        int y = r >> 8;
        int h = r & (H_ - 1);
        float d = xin_lat[b * H_ + h] - xout_lat[b * Y_ + y];
        wlatT[j] = (__bf16)__expf(cc * d * d);
    } else {
        int j = t - (NLON + NLAT);
        int o = j * 4;
        int b = o / (CP * W_ * H_);
        int r = o - b * (CP * W_ * H_);
        int co = r / (W_ * H_);
        int p = r & (W_ * H_ - 1);
        float4 v;
        bf16x4 ov;
        if (co == 0) {
            v = *(const float4*)&wt[((size_t)b * C_) * (W_ * H_) + p];
            ov[0] = (__bf16)((v.x != v.x) ? 0.f : 1.f);
            ov[1] = (__bf16)((v.y != v.y) ? 0.f : 1.f);
            ov[2] = (__bf16)((v.z != v.z) ? 0.f : 1.f);
            ov[3] = (__bf16)((v.w != v.w) ? 0.f : 1.f);
        } else {
            v = *(const float4*)&wt[((size_t)b * C_ + (co - 1)) * (W_ * H_) + p];
            ov[0] = (__bf16)((v.x != v.x) ? 0.f : v.x);
            ov[1] = (__bf16)((v.y != v.y) ? 0.f : v.y);
            ov[2] = (__bf16)((v.z != v.z) ? 0.f : v.z);
            ov[3] = (__bf16)((v.w != v.w) ? 0.f : v.w);
        }
        *(bf16x4*)&wt33[o] = ov;
    }
}

// ---------------- stage 1: U_T = (wt33 x wlatT^T)^T ----------------
// 128(w) x 64(y) x K256, 1056 blocks = 4/CU, 2-slot ring, counted
// vmcnt(3). Epilogue: LDS transpose -> 256B-span writes of U_T[b][ch][y][w].
__global__ __launch_bounds__(256, 4) void gemm_u(
    const __bf16* __restrict__ wt33, const __bf16* __restrict__ wlatT,
    __bf16* __restrict__ U_T)
{
    __shared__ union SM {
        struct { __bf16 A[2][4096]; __bf16 Bt[2][2048]; } t;  // 24 KB
        __bf16 th[8704];     // 64 x 136 (bf16 transpose, padded)
    } sm;

    const int t    = threadIdx.x;
    const int lane = t & 63;
    const int wave = t >> 6;
    const int wm   = wave >> 1, wn = wave & 1;
    const int lrow = lane & 15, lkg = lane >> 4;

    // bijective chunked XCD swizzle (1056 % 8 == 0): panel p's 16 tiles
    // land on one XCD -> wt33/wlatT panels L2-resident.
    const int xcd = blockIdx.x & 7, k = blockIdx.x >> 3;  // k: 0..131
    const int m   = xcd * 132 + k;
    const int p   = m >> 4, tile = m & 15;
    const int mtile = tile >> 3, ntile = tile & 7;        // 2(w) x 8(y)
    const int bb = (p >= CP) ? 1 : 0, chh = p - bb * CP;
    const __bf16* Abase = wt33 + (size_t)p * (W_ * H_) + (size_t)mtile * 128 * H_;
    const __bf16* Bbase = wlatT + (size_t)bb * (Y_ * H_) + (size_t)ntile * 64 * H_;

    auto stage = [&](int buf, int kt) {
#pragma unroll
        for (int j = 0; j < 2; ++j) {
            int f = j * 4 + wave;                          // A frags 0..7
            gload16_lds((const void*)(Abase + (f * 16 + lrow) * H_ + kt * 32 + lkg * 8),
                        (void*)&sm.t.A[buf][f * 512]);
        }
        gload16_lds((const void*)(Bbase + (wave * 16 + lrow) * H_ + kt * 32 + lkg * 8),
                    (void*)&sm.t.Bt[buf][wave * 512]);     // B frags 0..3
    };

    f32x4 acc[4][2] = {};
    stage(0, 0);
#pragma unroll
    for (int kt = 0; kt < 8; ++kt) {
        const int buf = kt & 1;
        if (kt < 7) {
            stage(buf ^ 1, kt + 1);
            asm volatile("s_waitcnt vmcnt(3)" ::: "memory");  // cur tile landed
        } else {
            asm volatile("s_waitcnt vmcnt(0)" ::: "memory");
        }
        __builtin_amdgcn_s_barrier();
        bf16x8 af[4], bf[2];
#pragma unroll
        for (int mt = 0; mt < 4; ++mt)
            af[mt] = *(const bf16x8*)&sm.t.A[buf][((wm * 4 + mt) * 64 + lane) * 8];
#pragma unroll
        for (int nt = 0; nt < 2; ++nt)
            bf[nt] = *(const bf16x8*)&sm.t.Bt[buf][((wn * 2 + nt) * 64 + lane) * 8];
#pragma unroll
        for (int mt = 0; mt < 4; ++mt)
#pragma unroll
            for (int nt = 0; nt < 2; ++nt)
                acc[mt][nt] = __builtin_amdgcn_mfma_f32_16x16x32_bf16(
                    af[mt], bf[nt], acc[mt][nt], 0, 0, 0);
        __builtin_amdgcn_sched_barrier(0);
        __builtin_amdgcn_s_barrier();
    }

    // block-cooperative bf16 transpose -> U_T rows [y][w], 256B spans
#pragma unroll
    for (int mt = 0; mt < 4; ++mt)
#pragma unroll
        for (int nt = 0; nt < 2; ++nt) {
            int yloc = wn * 32 + nt * 16 + lrow;
            int wloc = wm * 64 + mt * 16 + lkg * 4;
            f32x4 c = acc[mt][nt];
            bf16x4 v4;
            v4[0] = (__bf16)c[0]; v4[1] = (__bf16)c[1];
            v4[2] = (__bf16)c[2]; v4[3] = (__bf16)c[3];
            *(bf16x4*)&sm.th[yloc * 136 + wloc] = v4;
        }
    __syncthreads();
    __bf16* up = U_T + (size_t)(bb * CP + chh) * (Y_ * W_);
#pragma unroll
    for (int it = 0; it < 4; ++it) {
        int c2 = it * 256 + t;
        int y = c2 >> 4, w8 = c2 & 15;
        bf16x8 v = *(const bf16x8*)&sm.th[y * 136 + w8 * 8];
        *(bf16x8*)&up[(size_t)(ntile * 64 + y) * W_ + mtile * 128 + w8 * 8] = v;
    }
}

// ---------------- stage 2 fused: channel-merged, L2-resident combos ----
// Round-12 lesson: FETCH=51MB vs 9MB unique -> U_T thrashed per-XCD L2
// (old swizzle pinned (b,xt): 8.6MB working set > 4MB L2). New swizzle
// pins (b, channel-group) per XCD: working set = 5ch x 256KB + wlonT
// 256KB = 1.5MB < 4MB -> staging loads become L2 hits after cold fill,
// which the 1-ahead prefetch covers. 2-slot ring (48KB -> 3 blocks/CU).
// Per phase: stage 24KB (5 A-tiles + B k-slice), 12 ds_read, 20 MFMA;
// 8 phases. rec from acc[0]; C-quad = 4 consecutive y -> f32x4 stores.
__global__ __launch_bounds__(256, 2) void stage2_fused(
    const __bf16* __restrict__ wlonT, const __bf16* __restrict__ U_T,
    float* __restrict__ out)
{
    __shared__ __bf16 Ast[2][12288];    // 48 KB: 2 slots x (20 A + 4 B frags)

    const int t = threadIdx.x, lane = t & 63, wave = t >> 6;
    const int lrow = lane & 15, lkg = lane >> 4;
    const int wm = wave >> 1, wn = wave & 1;

    const int bid  = blockIdx.x;
    const int xcd  = bid & 7, q = bid >> 3;        // q: 0..127
    const int combo = (q >> 6) * 8 + xcd;          // 0..15: (b,g) per XCD
    const int b    = combo >> 3, g = combo & 7;
    const int tile = q & 63;
    const int yt   = tile >> 3, xt = tile & 7;
    const int x0   = xt * 64, y0 = yt * 64;

    const __bf16* lonp  = wlonT + ((size_t)b * X_ + x0) * W_;
    const __bf16* Ubase = U_T + ((size_t)b * CP) * (Y_ * W_) + (size_t)y0 * W_;

    // staging: 24 frags/phase (jf<20 -> A ch=jf>>2, row-quad jf&3;
    // jf>=20 -> B frag jf-20). Each wave stages frags wave*6..wave*6+5.
    auto stage = [&](int slot, int kt) {
#pragma unroll
        for (int i = 0; i < 6; ++i) {
            const int jf = wave * 6 + i;
            const __bf16* src;
            if (jf < 20) {
                const int jj = jf >> 2;
                const int ch = (jj == 0) ? 0 : (g * 4 + jj);
                src = Ubase + (size_t)ch * (Y_ * W_)
                      + ((jf & 3) * 16 + lrow) * W_ + kt * 32 + lkg * 8;
            } else {
                src = lonp + ((jf - 20) * 16 + lrow) * W_ + kt * 32 + lkg * 8;
            }
            gload16_lds((const void*)src, (void*)&Ast[slot][jf * 512]);
        }
    };

    stage(0, 0);

    f32x4 acc[5][2][2] = {};
#pragma unroll
    for (int kt = 0; kt < 8; ++kt) {
        const int slot = kt & 1;
        if (kt < 7) {
            stage(slot ^ 1, kt + 1);
            asm volatile("s_waitcnt vmcnt(6)" ::: "memory");   // phase kt landed
        } else {
            asm volatile("s_waitcnt vmcnt(0)" ::: "memory");
        }
        __builtin_amdgcn_s_barrier();
        bf16x8 af[5][2], bfv[2];
#pragma unroll
        for (int j = 0; j < 5; ++j)
#pragma unroll
            for (int mt = 0; mt < 2; ++mt)
                af[j][mt] = *(const bf16x8*)
                    &Ast[slot][((j * 4 + wm * 2 + mt) * 64 + lane) * 8];
#pragma unroll
        for (int nt = 0; nt < 2; ++nt)
            bfv[nt] = *(const bf16x8*)
                &Ast[slot][((20 + wn * 2 + nt) * 64 + lane) * 8];
        asm volatile("s_waitcnt lgkmcnt(0)" ::: "memory");
        __builtin_amdgcn_sched_barrier(0);
#pragma unroll
        for (int j = 0; j < 5; ++j)
#pragma unroll
            for (int mt = 0; mt < 2; ++mt)
#pragma unroll
                for (int nt = 0; nt < 2; ++nt)
                    acc[j][mt][nt] = __builtin_amdgcn_mfma_f32_16x16x32_bf16(
                        af[j][mt], bfv[nt], acc[j][mt][nt], 0, 0, 0);
        __builtin_amdgcn_sched_barrier(0);
        __builtin_amdgcn_s_barrier();   // slot safe to overwrite next phase
    }

    // ---- epilogue: rec from density acc, divide, store ----
    f32x4 rec[2][2];
#pragma unroll
    for (int mt = 0; mt < 2; ++mt)
#pragma unroll
        for (int nt = 0; nt < 2; ++nt) {
            f32x4 c = acc[0][mt][nt], q2;
#pragma unroll
            for (int rr = 0; rr < 4; ++rr)
                q2[rr] = 1.0f / fminf(fmaxf(c[rr], 1e-6f), 1e5f);
            rec[mt][nt] = q2;
        }
    if (g == 0) {
        float* outc = out + (size_t)(b * CP) * (X_ * Y_);
#pragma unroll
        for (int mt = 0; mt < 2; ++mt)
#pragma unroll
            for (int nt = 0; nt < 2; ++nt) {
                int xg = x0 + (wn * 2 + nt) * 16 + lrow;
                int yg = y0 + (wm * 2 + mt) * 16 + lkg * 4;
                *(f32x4*)&outc[(size_t)xg * Y_ + yg] = acc[0][mt][nt];
            }
    }
#pragma unroll
    for (int j = 1; j < 5; ++j) {
        float* outc = out + (size_t)(b * CP + g * 4 + j) * (size_t)(X_ * Y_);
#pragma unroll
        for (int mt = 0; mt < 2; ++mt)
#pragma unroll
            for (int nt = 0; nt < 2; ++nt) {
                int xg = x0 + (wn * 2 + nt) * 16 + lrow;
                int yg = y0 + (wm * 2 + mt) * 16 + lkg * 4;
                f32x4 v = acc[j][mt][nt] * rec[mt][nt];
                *(f32x4*)&outc[(size_t)xg * Y_ + yg] = v;
            }
    }
}

extern "C" void kernel_launch(void* const* d_in, const int* in_sizes, int n_in,
                              void* d_out, int out_size, void* d_ws, size_t ws_size,
                              hipStream_t stream)
{
    const float* xin_lon  = (const float*)d_in[0];
    const float* xin_lat  = (const float*)d_in[1];
    const float* wt       = (const float*)d_in[2];
    const float* xout_lon = (const float*)d_in[3];
    const float* xout_lat = (const float*)d_in[4];
    const float* init_ls  = (const float*)d_in[5];
    float* out = (float*)d_out;

    __bf16* wlonT = (__bf16*)d_ws;
    __bf16* wlatT = wlonT + (size_t)B_ * X_ * W_;
    __bf16* wt33  = wlatT + (size_t)B_ * Y_ * H_;
    __bf16* U_T   = wt33 + (size_t)B_ * CP * W_ * H_;

    prep_kernel<<<6272, 256, 0, stream>>>(xin_lon, xin_lat, xout_lon, xout_lat,
                                          init_ls, wt, wlonT, wlatT, wt33);
    gemm_u<<<1056, 256, 0, stream>>>(wt33, wlatT, U_T);
    stage2_fused<<<1024, 256, 0, stream>>>(wlonT, U_T, out);
}